// Round 3
// baseline (5859.259 us; speedup 1.0000x reference)
//
#include <hip/hip_runtime.h>
#include <stdint.h>

typedef unsigned short u16;
typedef unsigned int u32;
typedef __attribute__((ext_vector_type(8))) short bf16x8;   // 8 bf16 (4 VGPR)
typedef __attribute__((ext_vector_type(4))) float f32x4;
typedef __attribute__((ext_vector_type(8))) unsigned short u16x8;

#define DEV static __device__ __forceinline__

constexpr int T_ = 12, N_ = 2048;

DEV float bf2f(u16 u){ union{u32 i; float f;} v; v.i = ((u32)u)<<16; return v.f; }
DEV u16 f2bf(float f){ union{float f; u32 i;} v; v.f=f; u32 r = v.i + 0x7FFFu + ((v.i>>16)&1u); return (u16)(r>>16); }
DEV float geluf(float x){ return 0.5f*x*(1.f+erff(x*0.70710678118654752f)); }
DEV float softplusf(float x){ return fmaxf(x,0.f)+log1pf(expf(-fabsf(x))); }
DEV float sigmoidf_(float x){ return 1.f/(1.f+expf(-x)); }

// ---------------- transpose supports: sT[i][m][n] = s[i][n][m], fp32->bf16 ----------------
__global__ __launch_bounds__(256) void kT_s(const float* __restrict__ s, u16* __restrict__ sT){
  __shared__ float tile[32][33];
  const float* sp = s + (size_t)blockIdx.z*N_*N_;
  u16* dp = sT + (size_t)blockIdx.z*N_*N_;
  int m0 = blockIdx.x*32, n0 = blockIdx.y*32;
  int tx = threadIdx.x & 31, ty = threadIdx.x >> 5;
  #pragma unroll
  for(int i=0;i<32;i+=8) tile[ty+i][tx] = sp[(size_t)(n0+ty+i)*N_ + m0+tx];
  __syncthreads();
  #pragma unroll
  for(int i=0;i<32;i+=8) dp[(size_t)(m0+ty+i)*N_ + n0+tx] = f2bf(tile[tx][ty+i]);
}

// ---------------- transpose+cast the 6 weight mats of a layer to (C,K) bf16 ----------------
__global__ __launch_bounds__(256) void kT_w(const float* __restrict__ gw, const float* __restrict__ iw,
    const float* __restrict__ dw, const float* __restrict__ siw, const float* __restrict__ sow,
    const float* __restrict__ ow, u16* __restrict__ wt){
  const float* src; u16* dst; int K, C;
  switch(blockIdx.y){
    case 0: src=gw;  dst=wt+0;      K=640; C=128; break;
    case 1: src=iw;  dst=wt+81920;  K=128; C=512; break;
    case 2: src=dw;  dst=wt+147456; K=256; C=256; break;
    case 3: src=siw; dst=wt+212992; K=256; C=256; break;
    case 4: src=sow; dst=wt+278528; K=256; C=256; break;
    default:src=ow;  dst=wt+344064; K=256; C=128; break;
  }
  int idx = blockIdx.x*256 + threadIdx.x;
  if(idx < K*C){ int k = idx / C, c = idx - k*C; dst[c*K + k] = f2bf(src[idx]); }
}

// ---------------- h(chunk) -> hbf (rows,128) bf16 and hT (bt,128,2048) bf16 ----------------
__global__ __launch_bounds__(256) void k_prep_h(const float* __restrict__ h, u16* __restrict__ hbf,
                                                u16* __restrict__ hT){
  __shared__ float tile[32][33];
  int bt = blockIdx.z;
  int n0 = blockIdx.x*32, d0 = blockIdx.y*32;
  int tx = threadIdx.x & 31, ty = threadIdx.x >> 5;
  #pragma unroll
  for(int i=0;i<32;i+=8){
    float v = h[((size_t)bt*N_ + n0+ty+i)*128 + d0+tx];
    tile[ty+i][tx] = v;
    hbf[((size_t)bt*N_ + n0+ty+i)*128 + d0+tx] = f2bf(v);
  }
  __syncthreads();
  u16* ft = hT + (size_t)bt*262144;
  #pragma unroll
  for(int i=0;i<32;i+=8) ft[(size_t)(d0+ty+i)*2048 + n0+tx] = f2bf(tile[tx][ty+i]);
}

// ---------------- graph einsum: out[bt,m,d] = sum_n sT[m,n] * inT[bt,d,n]; MFMA bf16 ----------------
template<int WRT>
__global__ __launch_bounds__(256) void k_einsum(const u16* __restrict__ sT,
    const u16* __restrict__ inT, u16* __restrict__ fout, u16* __restrict__ outT){
  __shared__ u16 As[128*40];
  __shared__ u16 Bs[128*40];
  int tid = threadIdx.x;
  int bt = blockIdx.y, m0 = blockIdx.x*128;
  const u16* Bp = inT + (size_t)bt*262144;
  u16* Tp = outT + (size_t)bt*262144;
  int r = tid>>1, kq = (tid&1)*16;
  int w = tid>>6, lane = tid&63;
  int wm = (w>>1)*64, wc = (w&1)*64;
  int lr = lane&15, lk = (lane>>4)*8;
  f32x4 zero = {0.f,0.f,0.f,0.f};
  f32x4 acc[4][4];
  #pragma unroll
  for(int i=0;i<4;i++)
    #pragma unroll
    for(int j=0;j<4;j++) acc[i][j] = zero;
  for(int k0=0;k0<2048;k0+=32){
    const u16x8* pa = (const u16x8*)&sT[(size_t)(m0+r)*2048 + k0+kq];
    u16x8 a0 = pa[0], a1 = pa[1];
    const u16x8* pb = (const u16x8*)&Bp[(size_t)r*2048 + k0+kq];
    u16x8 b0 = pb[0], b1 = pb[1];
    *(u16x8*)&As[r*40+kq] = a0; *(u16x8*)&As[r*40+kq+8] = a1;
    *(u16x8*)&Bs[r*40+kq] = b0; *(u16x8*)&Bs[r*40+kq+8] = b1;
    __syncthreads();
    bf16x8 av[4], bv[4];
    #pragma unroll
    for(int i=0;i<4;i++) av[i] = *(const bf16x8*)&As[(wm+i*16+lr)*40 + lk];
    #pragma unroll
    for(int j=0;j<4;j++) bv[j] = *(const bf16x8*)&Bs[(wc+j*16+lr)*40 + lk];
    #pragma unroll
    for(int i=0;i<4;i++)
      #pragma unroll
      for(int j=0;j<4;j++)
        acc[i][j] = __builtin_amdgcn_mfma_f32_16x16x32_bf16(av[i], bv[j], acc[i][j], 0,0,0);
    __syncthreads();
  }
  size_t fb = (size_t)bt*N_;
  #pragma unroll
  for(int i=0;i<4;i++){
    int mb = m0 + wm + i*16 + ((lane>>4)<<2);
    #pragma unroll
    for(int j=0;j<4;j++){
      int d = wc + j*16 + lr;
      f32x4 v = acc[i][j];
      u16 q0=f2bf(v[0]), q1=f2bf(v[1]), q2=f2bf(v[2]), q3=f2bf(v[3]);
      fout[(fb + mb+0)*128 + d] = q0;
      fout[(fb + mb+1)*128 + d] = q1;
      fout[(fb + mb+2)*128 + d] = q2;
      fout[(fb + mb+3)*128 + d] = q3;
      if(WRT){
        ushort4 pk; pk.x=q0; pk.y=q1; pk.z=q2; pk.w=q3;
        *(ushort4*)&Tp[(size_t)d*2048 + mb] = pk;
      }
    }
  }
}

// ---------------- generic row-GEMM x WT(C,K) bf16, MFMA (all chunk-local rows) ----------------
// MODE 0: GCN  K=640 (5 slots of (rows,128), slot stride slotStride) -> z=bf16(gelu(acc+b))
// MODE 1: PR   K=128 A=(rows,128) -> sig/gate bf16 (cols 0..255 / 256..511)
// MODE 2: DSI  K=256 A=(rows,256) -> delta(softplus)/si(tanh)/so(tanh) bf16
// MODE 3: OUT  K=256 A=(rows,256) -> tp bf16
template<int MODE>
__global__ __launch_bounds__(256) void k_rowgemm(const u16* __restrict__ A, const u16* __restrict__ WT,
    size_t slotStride,
    const float* __restrict__ b0, const float* __restrict__ b1, const float* __restrict__ b2,
    u16* __restrict__ o0, u16* __restrict__ o1, u16* __restrict__ o2){
  constexpr int KT = (MODE==0)?640 : (MODE==1)?128 : 256;
  __shared__ u16 As[128*40];
  __shared__ u16 Bs[128*40];
  int tid = threadIdx.x;
  int c0 = blockIdx.x*128;
  size_t m0 = (size_t)blockIdx.y*128;
  int r = tid>>1, kq = (tid&1)*16;
  int w = tid>>6, lane = tid&63;
  int wm = (w>>1)*64, wc = (w&1)*64;
  int lr = lane&15, lk = (lane>>4)*8;
  f32x4 zero = {0.f,0.f,0.f,0.f};
  f32x4 acc[4][4];
  #pragma unroll
  for(int i=0;i<4;i++)
    #pragma unroll
    for(int j=0;j<4;j++) acc[i][j] = zero;
  for(int k0=0;k0<KT;k0+=32){
    size_t a_idx;
    if(MODE==0)      a_idx = (size_t)(k0>>7)*slotStride + (m0+r)*128 + (k0&127) + kq;
    else if(MODE==1) a_idx = (m0+r)*128 + k0 + kq;
    else             a_idx = (m0+r)*256 + k0 + kq;
    const u16x8* pa = (const u16x8*)&A[a_idx];
    u16x8 a0 = pa[0], a1 = pa[1];
    const u16x8* pb = (const u16x8*)&WT[(size_t)(c0+r)*KT + k0+kq];
    u16x8 w0 = pb[0], w1 = pb[1];
    *(u16x8*)&As[r*40+kq] = a0; *(u16x8*)&As[r*40+kq+8] = a1;
    *(u16x8*)&Bs[r*40+kq] = w0; *(u16x8*)&Bs[r*40+kq+8] = w1;
    __syncthreads();
    bf16x8 av[4], bv[4];
    #pragma unroll
    for(int i=0;i<4;i++) av[i] = *(const bf16x8*)&As[(wm+i*16+lr)*40 + lk];
    #pragma unroll
    for(int j=0;j<4;j++) bv[j] = *(const bf16x8*)&Bs[(wc+j*16+lr)*40 + lk];
    #pragma unroll
    for(int i=0;i<4;i++)
      #pragma unroll
      for(int j=0;j<4;j++)
        acc[i][j] = __builtin_amdgcn_mfma_f32_16x16x32_bf16(av[i], bv[j], acc[i][j], 0,0,0);
    __syncthreads();
  }
  int blk = c0>>8;
  const float* bs = (MODE==2) ? (blk==0?b0: blk==1?b1:b2) : b0;
  u16* ob = (MODE==2) ? (blk==0?o0: blk==1?o1:o2) : o0;
  #pragma unroll
  for(int i=0;i<4;i++){
    size_t mb = m0 + wm + i*16 + ((lane>>4)<<2);
    #pragma unroll
    for(int j=0;j<4;j++){
      int cg = c0 + wc + j*16 + lr;
      f32x4 v = acc[i][j];
      if(MODE==0){
        float bb = b0[cg];
        #pragma unroll
        for(int rr=0;rr<4;rr++) o0[(mb+rr)*128 + cg] = f2bf(geluf(v[rr]+bb));
      } else if(MODE==1){
        float bb = b0[cg];
        u16* buf = (cg<256)? o0 : o1;
        int cc = cg & 255;
        #pragma unroll
        for(int rr=0;rr<4;rr++) buf[(mb+rr)*256 + cc] = f2bf(v[rr]+bb);
      } else if(MODE==2){
        int cc = (c0&255) + wc + j*16 + lr;
        float bb = bs[cc];
        #pragma unroll
        for(int rr=0;rr<4;rr++){
          float x = v[rr]+bb;
          float y = (blk==0)? softplusf(x) : tanhf(x);
          ob[(mb+rr)*256 + cc] = f2bf(y);
        }
      } else {
        float bb = b0[cg];
        #pragma unroll
        for(int rr=0;rr<4;rr++) o0[(mb+rr)*128 + cg] = f2bf(v[rr]+bb);
      }
    }
  }
}

// ---------------- depthwise causal conv over T (K=4) + SiLU, in-place, CB-batch chunk ----------------
__global__ __launch_bounds__(256) void k_conv(u16* __restrict__ sig, const float* __restrict__ cw,
                                              const float* __restrict__ cb){
  int idx = blockIdx.x*256 + threadIdx.x;     // CB*2048*256 threads
  int c = idx & 255;
  int bn = idx >> 8;
  int b = bn >> 11, n = bn & 2047;
  float w0=cw[c*4], w1=cw[c*4+1], w2=cw[c*4+2], w3=cw[c*4+3], bias=cb[c];
  const size_t tstr = (size_t)N_*256;
  size_t base = ((size_t)b*T_*N_ + n)*256 + c;
  float x[T_];
  #pragma unroll
  for(int t=0;t<T_;t++) x[t] = bf2f(sig[base + (size_t)t*tstr]);
  #pragma unroll
  for(int t=0;t<T_;t++){
    float a = bias + w3*x[t];
    if(t>0) a += w2*x[t-1];
    if(t>1) a += w1*x[t-2];
    if(t>2) a += w0*x[t-3];
    sig[base + (size_t)t*tstr] = f2bf(a * sigmoidf_(a));
  }
}

// ---------------- selective-scan over T + gate; hid written over gate (CB-batch chunk) ----------------
__global__ __launch_bounds__(256) void k_scan(const u16* __restrict__ sig, u16* __restrict__ gate,
    const u16* __restrict__ delta, const u16* __restrict__ siB, const u16* __restrict__ soB,
    const float* __restrict__ alog, const float* __restrict__ dskip){
  int idx = blockIdx.x*256 + threadIdx.x;
  int c = idx & 255;
  int bn = idx >> 8;
  int b = bn >> 11, n = bn & 2047;
  float a = -softplusf(alog[c]);
  float dk = dskip[c];
  const size_t tstr = (size_t)N_*256;
  size_t base = ((size_t)b*T_*N_ + n)*256 + c;
  float st = 0.f;
  #pragma unroll
  for(int t=0;t<T_;t++){
    size_t o = base + (size_t)t*tstr;
    float sg = bf2f(sig[o]);
    float dl = bf2f(delta[o]);
    float siv = bf2f(siB[o]);
    float sov = bf2f(soB[o]);
    float gt = bf2f(gate[o]);
    st = expf(dl*a)*st + siv*sg;
    float y = sov*st + dk*sg;
    gate[o] = f2bf(y * sigmoidf_(gt));
  }
}

// ---------------- fused = h + sp + tp + sp*tp ; LayerNorm(D=128) ----------------
__global__ __launch_bounds__(256) void k_fuse_ln(const float* __restrict__ h, const u16* __restrict__ sp,
    const u16* __restrict__ tp, const float* __restrict__ g, const float* __restrict__ bb,
    float* __restrict__ out){
  int w = threadIdx.x>>6, lane = threadIdx.x&63;
  size_t row = (size_t)blockIdx.x*4 + w;
  size_t p = row*128;
  float h0=h[p+lane], h1=h[p+64+lane];
  float s0=bf2f(sp[p+lane]), s1=bf2f(sp[p+64+lane]);
  float t0=bf2f(tp[p+lane]), t1=bf2f(tp[p+64+lane]);
  float v0 = h0 + s0 + t0 + s0*t0;
  float v1 = h1 + s1 + t1 + s1*t1;
  float sum = v0+v1;
  #pragma unroll
  for(int o=32;o>=1;o>>=1) sum += __shfl_xor(sum, o);
  float mean = sum*(1.f/128.f);
  float e0=v0-mean, e1=v1-mean;
  float vv = e0*e0 + e1*e1;
  #pragma unroll
  for(int o=32;o>=1;o>>=1) vv += __shfl_xor(vv, o);
  float inv = rsqrtf(vv*(1.f/128.f) + 1e-5f);
  out[p+lane]    = e0*inv*g[lane]    + bb[lane];
  out[p+64+lane] = e1*inv*g[lane+64] + bb[lane+64];
}

extern "C" void kernel_launch(void* const* d_in, const int* in_sizes, int n_in,
                              void* d_out, int out_size, void* d_ws, size_t ws_size,
                              hipStream_t stream){
  const float* inp =(const float*)d_in[0];
  const float* sup =(const float*)d_in[1];
  const float* gw  =(const float*)d_in[2];
  const float* gb  =(const float*)d_in[3];
  const float* iw  =(const float*)d_in[4];
  const float* ib  =(const float*)d_in[5];
  const float* cw  =(const float*)d_in[6];
  const float* cb  =(const float*)d_in[7];
  const float* dw  =(const float*)d_in[8];
  const float* db  =(const float*)d_in[9];
  const float* siw =(const float*)d_in[10];
  const float* sib =(const float*)d_in[11];
  const float* sow =(const float*)d_in[12];
  const float* sob =(const float*)d_in[13];
  const float* alog=(const float*)d_in[14];
  const float* dsk =(const float*)d_in[15];
  const float* ow  =(const float*)d_in[16];
  const float* ob  =(const float*)d_in[17];
  const float* lng =(const float*)d_in[18];
  const float* lnb =(const float*)d_in[19];
  float* out = (float*)d_out;

  // ---- adaptive chunking over batch: pick largest CB with 13 units fitting ws ----
  // header: sTb (16 MiB) + wt (0.72 MiB) at fixed offsets; units start at 17,825,792.
  // unit = CB*24576 rows * 128 cols * 2 B = CB*6,291,456 B.  13 units needed.
  int CB = 1;
  if      (17825792ull + 13ull*16*6291456ull <= ws_size) CB = 16;
  else if (17825792ull + 13ull* 8*6291456ull <= ws_size) CB = 8;
  else if (17825792ull + 13ull* 4*6291456ull <= ws_size) CB = 4;
  else if (17825792ull + 13ull* 2*6291456ull <= ws_size) CB = 2;
  const int NC  = 16/CB;               // chunks
  const int BTc = CB*T_;               // bt slices per chunk
  const size_t Rc = (size_t)CB*24576;  // rows per chunk
  const size_t U  = (size_t)CB*6291456ull; // unit bytes

  char* Wp = (char*)d_ws;
  u16* sTb = (u16*)(Wp);
  u16* wt  = (u16*)(Wp + 16777216ull);
  char* UB = Wp + 17825792ull;
  u16* hbf  = (u16*)(UB + 0*U);
  u16* f1   = (u16*)(UB + 1*U);
  u16* f2   = (u16*)(UB + 2*U);
  u16* f3   = (u16*)(UB + 3*U);
  u16* f4   = (u16*)(UB + 4*U);
  u16* hT   = (u16*)(UB + 5*U);
  u16* hop  = (u16*)(UB + 6*U);
  u16* z    = (u16*)(UB + 7*U);
  u16* tp   = (u16*)(UB + 8*U);
  u16* si_  = (u16*)(UB + 9*U);
  u16* so_  = (u16*)(UB + 11*U);
  // overlays (dead by the time they're written):
  u16* sig   = f1;   // units 1-2 (f1,f2 dead after GCN)
  u16* gate  = f3;   // units 3-4
  u16* delta = hT;   // units 5-6 (hT,hop dead after einsums)

  hipLaunchKernelGGL(kT_s, dim3(64,64,2), dim3(256),0,stream, sup, sTb);

  for(int l=0;l<2;l++){
    const float* hfull = l ? out : inp;
    hipLaunchKernelGGL(kT_w, dim3(320,6), dim3(256),0,stream,
        gw + (size_t)l*81920, iw + (size_t)l*65536, dw + (size_t)l*65536,
        siw + (size_t)l*65536, sow + (size_t)l*65536, ow + (size_t)l*32768, wt);
    for(int c=0;c<NC;c++){
      const float* h = hfull + (size_t)c*Rc*128;
      float* oc = out + (size_t)c*Rc*128;
      const u16* s0 = sTb;
      const u16* s1 = sTb + 4194304ull;
      hipLaunchKernelGGL(k_prep_h, dim3(64,4,BTc), dim3(256),0,stream, h, hbf, hT);
      hipLaunchKernelGGL((k_einsum<1>), dim3(16,BTc), dim3(256),0,stream, s0, hT,  f1, hop);
      hipLaunchKernelGGL((k_einsum<0>), dim3(16,BTc), dim3(256),0,stream, s0, hop, f2, hop);
      hipLaunchKernelGGL((k_einsum<1>), dim3(16,BTc), dim3(256),0,stream, s1, hT,  f3, hop);
      hipLaunchKernelGGL((k_einsum<0>), dim3(16,BTc), dim3(256),0,stream, s1, hop, f4, hop);
      hipLaunchKernelGGL((k_rowgemm<0>), dim3(1,Rc/128), dim3(256),0,stream, hbf, wt, (size_t)Rc*128,
          gb + (size_t)l*128, nullptr, nullptr, z, nullptr, nullptr);
      hipLaunchKernelGGL((k_rowgemm<1>), dim3(4,Rc/128), dim3(256),0,stream, hbf, wt+81920, 0ull,
          ib + (size_t)l*512, nullptr, nullptr, sig, gate, nullptr);
      hipLaunchKernelGGL(k_conv, dim3(CB*2048), dim3(256),0,stream, sig,
          cw + (size_t)l*1024, cb + (size_t)l*256);
      hipLaunchKernelGGL((k_rowgemm<2>), dim3(6,Rc/128), dim3(256),0,stream, sig, wt+147456, 0ull,
          db + (size_t)l*256, sib + (size_t)l*256, sob + (size_t)l*256, delta, si_, so_);
      hipLaunchKernelGGL(k_scan, dim3(CB*2048), dim3(256),0,stream, sig, gate, delta, si_, so_,
          alog + (size_t)l*256, dsk + (size_t)l*256);
      hipLaunchKernelGGL((k_rowgemm<3>), dim3(1,Rc/128), dim3(256),0,stream, gate, wt+344064, 0ull,
          ob + (size_t)l*128, nullptr, nullptr, tp, nullptr, nullptr);
      hipLaunchKernelGGL(k_fuse_ln, dim3(Rc/4), dim3(256),0,stream, h, z, tp,
          lng + (size_t)l*128, lnb + (size_t)l*128, oc);
    }
  }
}